// Round 2
// baseline (4025.905 us; speedup 1.0000x reference)
//
#include <hip/hip_runtime.h>
#include <cstdint>
#include <cstddef>

// ---------------------------------------------------------------------------
// Transformer (enc-dec) forward on MI355X. Round 1: fp32 global tensors
// (per harness contract — reference is float32), bf16 conversion at LDS
// staging, fp32 accumulate, fp32 residual/LN path.
// ---------------------------------------------------------------------------

#define B_   4
#define S_   512
#define D_   512
#define H_   8
#define L_   6
#define DFF_ 2048
#define VD_  32000

typedef unsigned short u16;
typedef short  s16x8  __attribute__((ext_vector_type(8)));
typedef __bf16 bf16x8 __attribute__((ext_vector_type(8)));
typedef float  f32x4  __attribute__((ext_vector_type(4)));

__device__ __forceinline__ u16 f2b(float f) {
    __bf16 h = (__bf16)f; return __builtin_bit_cast(u16, h);
}
__device__ __forceinline__ bf16x8 ld_frag(const u16* p) {
    return __builtin_bit_cast(bf16x8, *(const s16x8*)p);
}
// load 8 consecutive floats, convert to bf16, store 16B to LDS
__device__ __forceinline__ void cvt8(const float* __restrict__ g, u16* l) {
    float4 x = *(const float4*)g;
    float4 y = *(const float4*)(g + 4);
    bf16x8 o;
    o[0] = (__bf16)x.x; o[1] = (__bf16)x.y; o[2] = (__bf16)x.z; o[3] = (__bf16)x.w;
    o[4] = (__bf16)y.x; o[5] = (__bf16)y.y; o[6] = (__bf16)y.z; o[7] = (__bf16)y.w;
    *(s16x8*)l = __builtin_bit_cast(s16x8, o);
}
__device__ __forceinline__ float wsum(float x) {
#pragma unroll
    for (int m = 32; m > 0; m >>= 1) x += __shfl_xor(x, m, 64);
    return x;
}
__device__ __forceinline__ float wmaxr(float x) {
#pragma unroll
    for (int m = 32; m > 0; m >>= 1) x = fmaxf(x, __shfl_xor(x, m, 64));
    return x;
}

// ---------------------------------------------------------------------------
// Embedding + positional encoding (fp32 in/out).
// PE faithful: angle = pos * 10000^(-d/256); col0 forced 0, row0 all zeros;
// even cols sin, odd cols cos (rows >= 1 only).
// ---------------------------------------------------------------------------
__global__ __launch_bounds__(256) void embed_k(const int* __restrict__ idx,
                                               const float* __restrict__ emb,
                                               float* __restrict__ out)
{
    int rs = blockIdx.x;          // [0, B*S)
    int s  = rs & (S_ - 1);
    int tok = idx[rs];
#pragma unroll
    for (int i = 0; i < 2; ++i) {
        int d = threadIdx.x + i * 256;
        float e  = emb[(size_t)tok * D_ + d];
        float pe = 0.0f;
        if (s > 0 && d > 0) {
            float ang = (float)s * expf(-(float)d * 0.035977892078031968f); // ln(1e4)/256
            pe = (d & 1) ? cosf(ang) : sinf(ang);
        }
        out[(size_t)rs * D_ + d] = e + pe;
    }
}

// ---------------------------------------------------------------------------
// Generic GEMM: C[M,N] = act(A[M,K] @ B[K,N] + bias). A,B fp32 row-major
// (converted to bf16 at staging). 128x128 tile, BK=32, 256 thr, 16x16x32 MFMA.
// blockIdx.z selects one of up to 3 (B, bias, O) triples (QKV batching).
// act: leaky_relu 0.01. Output fp32.
// ---------------------------------------------------------------------------
#define SPA 40
#define SPB 130

__global__ __launch_bounds__(256) void gemm_k(
    const float* __restrict__ A,
    const float* B0, const float* B1, const float* B2,
    const float* bias0, const float* bias1, const float* bias2,
    float* O0, float* O1, float* O2,
    int M, int N, int K, int act)
{
    const float* Bm   = blockIdx.z == 0 ? B0 : (blockIdx.z == 1 ? B1 : B2);
    const float* bias = blockIdx.z == 0 ? bias0 : (blockIdx.z == 1 ? bias1 : bias2);
    float* O          = blockIdx.z == 0 ? O0 : (blockIdx.z == 1 ? O1 : O2);

    __shared__ u16 As[128 * SPA];
    __shared__ u16 Bs[32 * SPB];

    const int t = threadIdx.x;
    const int lane = t & 63, wave = t >> 6;
    const int q = lane >> 4, r16 = lane & 15;
    const int wm = (wave & 1) * 64, wn = (wave >> 1) * 64;
    const int m0 = blockIdx.y * 128, n0 = blockIdx.x * 128;

    f32x4 acc[4][4] = {};

    for (int k0 = 0; k0 < K; k0 += 32) {
#pragma unroll
        for (int r = 0; r < 2; ++r) {                 // A tile 128x32
            int uu = t + r * 256;
            int row = uu >> 2, c8 = uu & 3;
            cvt8(A + (size_t)(m0 + row) * K + k0 + c8 * 8, As + row * SPA + c8 * 8);
        }
#pragma unroll
        for (int r = 0; r < 2; ++r) {                 // B tile 32x128 (row-major)
            int uu = t + r * 256;
            int krow = uu >> 4, n8 = uu & 15;
            cvt8(Bm + (size_t)(k0 + krow) * N + n0 + n8 * 8, Bs + krow * SPB + n8 * 8);
        }
        __syncthreads();

        bf16x8 af[4];
#pragma unroll
        for (int fm = 0; fm < 4; ++fm)
            af[fm] = ld_frag(As + (wm + fm * 16 + r16) * SPA + q * 8);
        bf16x8 bf[4];
#pragma unroll
        for (int fn = 0; fn < 4; ++fn) {              // column gather (scalar reads)
            s16x8 tmp;
#pragma unroll
            for (int j = 0; j < 8; ++j)
                tmp[j] = (short)Bs[(q * 8 + j) * SPB + wn + fn * 16 + r16];
            bf[fn] = __builtin_bit_cast(bf16x8, tmp);
        }
#pragma unroll
        for (int fm = 0; fm < 4; ++fm)
#pragma unroll
            for (int fn = 0; fn < 4; ++fn)
                acc[fm][fn] = __builtin_amdgcn_mfma_f32_16x16x32_bf16(
                    af[fm], bf[fn], acc[fm][fn], 0, 0, 0);
        __syncthreads();
    }

#pragma unroll
    for (int fn = 0; fn < 4; ++fn) {
        int col = n0 + wn + fn * 16 + r16;
        float bv = bias ? bias[col] : 0.0f;
#pragma unroll
        for (int fm = 0; fm < 4; ++fm) {
#pragma unroll
            for (int rg = 0; rg < 4; ++rg) {
                int rowg = m0 + wm + fm * 16 + q * 4 + rg;  // C: col=lane&15, row=quad*4+reg
                float x = acc[fm][fn][rg] + bv;
                if (act) x = x >= 0.0f ? x : 0.01f * x;
                O[(size_t)rowg * N + col] = x;
            }
        }
    }
}

// ---------------------------------------------------------------------------
// Attention scores: Sc[bh,q,k] = (Q . K)/8, fp32 out. grid (4,4,B*H).
// K-operand is key-row-major -> both frags are b128 LDS loads.
// ---------------------------------------------------------------------------
__global__ __launch_bounds__(256) void scores_k(const float* __restrict__ Qb,
                                                const float* __restrict__ Kb,
                                                float* __restrict__ Sc)
{
    __shared__ u16 Qs[128 * 72];
    __shared__ u16 Ks[128 * 72];
    const int t = threadIdx.x;
    const int lane = t & 63, wave = t >> 6;
    const int q = lane >> 4, r16 = lane & 15;
    const int wm = (wave & 1) * 64, wn = (wave >> 1) * 64;
    const int n0 = blockIdx.x * 128, m0 = blockIdx.y * 128;
    const int bh = blockIdx.z, b = bh >> 3, h = bh & 7;
    const size_t base = (size_t)b * S_ * D_ + h * 64;

#pragma unroll
    for (int r = 0; r < 4; ++r) {
        int uu = t + r * 256;
        int row = uu >> 3, c8 = uu & 7;
        cvt8(Qb + base + (size_t)(m0 + row) * D_ + c8 * 8, Qs + row * 72 + c8 * 8);
        cvt8(Kb + base + (size_t)(n0 + row) * D_ + c8 * 8, Ks + row * 72 + c8 * 8);
    }
    __syncthreads();

    f32x4 acc[4][4] = {};
#pragma unroll
    for (int kk = 0; kk < 2; ++kk) {
        bf16x8 af[4], bf[4];
#pragma unroll
        for (int fm = 0; fm < 4; ++fm)
            af[fm] = ld_frag(Qs + (wm + fm * 16 + r16) * 72 + kk * 32 + q * 8);
#pragma unroll
        for (int fn = 0; fn < 4; ++fn)
            bf[fn] = ld_frag(Ks + (wn + fn * 16 + r16) * 72 + kk * 32 + q * 8);
#pragma unroll
        for (int fm = 0; fm < 4; ++fm)
#pragma unroll
            for (int fn = 0; fn < 4; ++fn)
                acc[fm][fn] = __builtin_amdgcn_mfma_f32_16x16x32_bf16(
                    af[fm], bf[fn], acc[fm][fn], 0, 0, 0);
    }

#pragma unroll
    for (int fn = 0; fn < 4; ++fn) {
        int col = n0 + wn + fn * 16 + r16;
#pragma unroll
        for (int fm = 0; fm < 4; ++fm)
#pragma unroll
            for (int rg = 0; rg < 4; ++rg) {
                int rowg = m0 + wm + fm * 16 + q * 4 + rg;
                Sc[((size_t)bh * S_ + rowg) * S_ + col] = 0.125f * acc[fm][fn][rg];
            }
    }
}

// ---------------------------------------------------------------------------
// Mask + softmax. Faithful: masked entries = 1e-9 BEFORE softmax (still
// contribute exp(1e-9 - max)). Wave per row; P out bf16.
// ---------------------------------------------------------------------------
__global__ __launch_bounds__(256) void softmax_k(const float* __restrict__ Sc,
                                                 u16* __restrict__ P,
                                                 const int* __restrict__ tok,
                                                 int causal)
{
    const int wave = threadIdx.x >> 6, lane = threadIdx.x & 63;
    const int row = blockIdx.x * 4 + wave;      // [0, B*H*S)
    const int qi = row & (S_ - 1), b = row >> 12;   // bh = row>>9, b = bh>>3
    const float* sr = Sc + (size_t)row * S_;
    const int* kb = tok + b * S_;

    float v[8];
    float mx = -3.0e38f;
#pragma unroll
    for (int i = 0; i < 8; ++i) {
        int k = i * 64 + lane;
        float x = sr[k];
        bool msk = (kb[k] == 0) || (causal && (k > qi));
        x = msk ? 1e-9f : x;
        v[i] = x;
        mx = fmaxf(mx, x);
    }
    mx = wmaxr(mx);
    float s = 0.0f;
#pragma unroll
    for (int i = 0; i < 8; ++i) { v[i] = __expf(v[i] - mx); s += v[i]; }
    s = wsum(s);
    float inv = 1.0f / s;
#pragma unroll
    for (int i = 0; i < 8; ++i)
        P[(size_t)row * S_ + i * 64 + lane] = f2b(v[i] * inv);
}

// ---------------------------------------------------------------------------
// PV: attn[b, q, h*64+d] = sum_k P[bh,q,k] * V[b,k,h*64+d]. grid (S/64, B*H).
// P bf16, V fp32 (converted at staging), out fp32.
// ---------------------------------------------------------------------------
__global__ __launch_bounds__(256) void pv_k(const u16* __restrict__ P,
                                            const float* __restrict__ Vb,
                                            float* __restrict__ attnb)
{
    __shared__ u16 Ps[64 * SPA];
    __shared__ u16 Vs[32 * 66];
    const int t = threadIdx.x;
    const int lane = t & 63, wave = t >> 6;
    const int q = lane >> 4, r16 = lane & 15;
    const int m0 = blockIdx.x * 64;
    const int bh = blockIdx.y, b = bh >> 3, h = bh & 7;

    f32x4 acc[4] = {};
    for (int k0 = 0; k0 < S_; k0 += 32) {
        {
            int row = t >> 2, c8 = t & 3;           // P tile 64x32 (bf16 copy)
            *(uint4*)(Ps + row * SPA + c8 * 8) =
                *(const uint4*)(P + ((size_t)bh * S_ + m0 + row) * S_ + k0 + c8 * 8);
            int krow = t >> 3, n8 = t & 7;          // V tile 32x64 (fp32 -> bf16)
            cvt8(Vb + ((size_t)b * S_ + k0 + krow) * D_ + h * 64 + n8 * 8,
                 Vs + krow * 66 + n8 * 8);
        }
        __syncthreads();
        bf16x8 a = ld_frag(Ps + (wave * 16 + r16) * SPA + q * 8);
#pragma unroll
        for (int fn = 0; fn < 4; ++fn) {
            s16x8 tmp;
#pragma unroll
            for (int j = 0; j < 8; ++j)
                tmp[j] = (short)Vs[(q * 8 + j) * 66 + fn * 16 + r16];
            acc[fn] = __builtin_amdgcn_mfma_f32_16x16x32_bf16(
                a, __builtin_bit_cast(bf16x8, tmp), acc[fn], 0, 0, 0);
        }
        __syncthreads();
    }
#pragma unroll
    for (int fn = 0; fn < 4; ++fn)
#pragma unroll
        for (int rg = 0; rg < 4; ++rg)
            attnb[((size_t)b * S_ + m0 + wave * 16 + q * 4 + rg) * D_ + h * 64 + fn * 16 + r16]
                = acc[fn][rg];
}

// ---------------------------------------------------------------------------
// LayerNorm: out = LN(x32 + resid) * g + b  (wave per row of 512, fp32)
// resid/out may alias (in-place): each element read+written by same lane.
// ---------------------------------------------------------------------------
__global__ __launch_bounds__(256) void ln_k(const float* __restrict__ X32,
                                            const float* resid,
                                            const float* __restrict__ g,
                                            const float* __restrict__ be,
                                            float* out)
{
    const int wave = threadIdx.x >> 6, lane = threadIdx.x & 63;
    const int row = blockIdx.x * 4 + wave;
    const float* xr = X32 + (size_t)row * D_;
    const float* rr = resid + (size_t)row * D_;

    float v[8];
    float s = 0.0f;
#pragma unroll
    for (int i = 0; i < 8; ++i) {
        v[i] = xr[i * 64 + lane] + rr[i * 64 + lane];
        s += v[i];
    }
    s = wsum(s);
    float mean = s * (1.0f / D_);
    float s2 = 0.0f;
#pragma unroll
    for (int i = 0; i < 8; ++i) { float d = v[i] - mean; s2 += d * d; }
    s2 = wsum(s2);
    float inv = rsqrtf(s2 * (1.0f / D_) + 1e-6f);
#pragma unroll
    for (int i = 0; i < 8; ++i) {
        int c = i * 64 + lane;
        out[(size_t)row * D_ + c] = (v[i] - mean) * inv * g[c] + be[c];
    }
}

// ---------------------------------------------------------------------------
// Host-side orchestration
// ---------------------------------------------------------------------------
extern "C" void kernel_launch(void* const* d_in, const int* in_sizes, int n_in,
                              void* d_out, int out_size, void* d_ws, size_t ws_size,
                              hipStream_t stream)
{
    (void)in_sizes; (void)n_in; (void)out_size; (void)ws_size;

    const int*   enc_in  = (const int*)d_in[0];
    const int*   dec_in  = (const int*)d_in[1];
    const float* emb_enc = (const float*)d_in[2];
    const float* emb_dec = (const float*)d_in[3];
    const float* proj_W  = (const float*)d_in[4];
    // per prefix: 0 Wq 1 Wk 2 Wv 3 Wo 4 g1 5 b1 6 W1 7 c1 8 W2 9 c2 10 g2 11 b2
    const float* Wt[2][12];
    for (int p = 0; p < 2; ++p)
        for (int j = 0; j < 12; ++j)
            Wt[p][j] = (const float*)d_in[5 + p * 12 + j];

    // workspace layout (1 MB units). total 76 MB.
    char* ws = (char*)d_ws;
    const size_t MB = 1024 * 1024;
    float* Xe  = (float*)(ws + 0 * MB);    // [2048,512] f32, 4 MB (enc act / enc_out)
    float* Xd  = (float*)(ws + 4 * MB);    // [2048,512] f32 (dec act)
    float* Qb  = (float*)(ws + 8 * MB);
    float* Kb  = (float*)(ws + 12 * MB);
    float* Vb  = (float*)(ws + 16 * MB);
    float* Atn = (float*)(ws + 20 * MB);   // attention context [2048,512]
    float* Fo  = (float*)(ws + 24 * MB);   // pre-LN matmul out [2048,512]
    float* Sc  = (float*)(ws + 28 * MB);   // scores [32,512,512] f32, 32 MB
    float* Hid = (float*)(ws + 28 * MB);   // FFN hidden [2048,2048] f32, 16 MB (shares w/ Sc)
    u16*   Pm  = (u16*)(ws + 60 * MB);     // probs [32,512,512] bf16, 16 MB

    const dim3 blk(256);
    auto gemm = [&](const float* A, const float* B0p, const float* B1p, const float* B2p,
                    const float* c0, const float* c1p, const float* c2p,
                    float* O0, float* O1, float* O2,
                    int M, int N, int K, int nz, int act) {
        dim3 g(N / 128, M / 128, nz);
        gemm_k<<<g, blk, 0, stream>>>(A, B0p, B1p, B2p, c0, c1p, c2p, O0, O1, O2,
                                      M, N, K, act);
    };
    auto attention = [&](const float* Xq, const float* Xkv, const int* mtok, int causal,
                         const float* Wq, const float* Wk, const float* Wv) {
        if (Xq == Xkv) {
            gemm(Xq, Wq, Wk, Wv, 0, 0, 0, Qb, Kb, Vb, 2048, 512, 512, 3, 0);
        } else {
            gemm(Xq, Wq, 0, 0, 0, 0, 0, Qb, 0, 0, 2048, 512, 512, 1, 0);
            gemm(Xkv, Wk, Wv, 0, 0, 0, 0, Kb, Vb, 0, 2048, 512, 512, 2, 0);
        }
        scores_k<<<dim3(4, 4, 32), blk, 0, stream>>>(Qb, Kb, Sc);
        softmax_k<<<dim3(4096), blk, 0, stream>>>(Sc, Pm, mtok, causal);
        pv_k<<<dim3(8, 32), blk, 0, stream>>>(Pm, Vb, Atn);
    };

    // ---------------- encoder ----------------
    embed_k<<<B_ * S_, blk, 0, stream>>>(enc_in, emb_enc, Xe);
    for (int l = 0; l < L_; ++l) {
        const float* Wq = Wt[0][0] + (size_t)l * D_ * D_;
        const float* Wk = Wt[0][1] + (size_t)l * D_ * D_;
        const float* Wv = Wt[0][2] + (size_t)l * D_ * D_;
        const float* Wo = Wt[0][3] + (size_t)l * D_ * D_;
        const float* g1 = Wt[0][4] + l * D_;
        const float* b1 = Wt[0][5] + l * D_;
        const float* W1 = Wt[0][6] + (size_t)l * D_ * DFF_;
        const float* c1 = Wt[0][7] + l * DFF_;
        const float* W2 = Wt[0][8] + (size_t)l * DFF_ * D_;
        const float* c2 = Wt[0][9] + l * D_;
        const float* g2 = Wt[0][10] + l * D_;
        const float* b2 = Wt[0][11] + l * D_;

        attention(Xe, Xe, enc_in, 0, Wq, Wk, Wv);
        gemm(Atn, Wo, 0, 0, 0, 0, 0, Fo, 0, 0, 2048, 512, 512, 1, 0);
        ln_k<<<dim3(512), blk, 0, stream>>>(Fo, Xe, g1, b1, Xe);
        gemm(Xe, W1, 0, 0, c1, 0, 0, Hid, 0, 0, 2048, 2048, 512, 1, 1);
        gemm(Hid, W2, 0, 0, c2, 0, 0, Fo, 0, 0, 2048, 512, 2048, 1, 0);
        ln_k<<<dim3(512), blk, 0, stream>>>(Fo, Xe, g2, b2, Xe);
    }

    // ---------------- decoder ----------------
    embed_k<<<B_ * S_, blk, 0, stream>>>(dec_in, emb_dec, Xd);
    for (int l = 0; l < L_; ++l) {
        const float* Wq = Wt[1][0] + (size_t)l * D_ * D_;
        const float* Wk = Wt[1][1] + (size_t)l * D_ * D_;
        const float* Wv = Wt[1][2] + (size_t)l * D_ * D_;
        const float* Wo = Wt[1][3] + (size_t)l * D_ * D_;
        const float* g1 = Wt[1][4] + l * D_;
        const float* b1 = Wt[1][5] + l * D_;
        const float* W1 = Wt[1][6] + (size_t)l * D_ * DFF_;
        const float* c1 = Wt[1][7] + l * DFF_;
        const float* W2 = Wt[1][8] + (size_t)l * DFF_ * D_;
        const float* c2 = Wt[1][9] + l * D_;
        const float* g2 = Wt[1][10] + l * D_;
        const float* b2 = Wt[1][11] + l * D_;

        // self-attention (causal + dec pad)
        attention(Xd, Xd, dec_in, 1, Wq, Wk, Wv);
        gemm(Atn, Wo, 0, 0, 0, 0, 0, Fo, 0, 0, 2048, 512, 512, 1, 0);
        ln_k<<<dim3(512), blk, 0, stream>>>(Fo, Xd, g1, b1, Xd);

        // cross-attention (same weights, K/V from enc_out, enc pad mask)
        attention(Xd, Xe, enc_in, 0, Wq, Wk, Wv);
        gemm(Atn, Wo, 0, 0, 0, 0, 0, Fo, 0, 0, 2048, 512, 512, 1, 0);
        ln_k<<<dim3(512), blk, 0, stream>>>(Fo, Xd, g1, b1, Xd);

        // FFN
        gemm(Xd, W1, 0, 0, c1, 0, 0, Hid, 0, 0, 2048, 2048, 512, 1, 1);
        gemm(Hid, W2, 0, 0, c2, 0, 0, Fo, 0, 0, 2048, 512, 2048, 1, 0);
        ln_k<<<dim3(512), blk, 0, stream>>>(Fo, Xd, g2, b2, Xd);
    }

    // final projection to vocab (fp32 out)
    gemm(Xd, proj_W, 0, 0, 0, 0, 0, (float*)d_out, 0, 0, 2048, VD_, 512, 1, 0);
}